// Round 13
// baseline (160.645 us; speedup 1.0000x reference)
//
#include <hip/hip_runtime.h>
#include <hip/hip_bf16.h>

typedef unsigned int u32;
typedef unsigned short u16;
typedef __attribute__((ext_vector_type(8))) short bfrag;   // 8 x bf16 MFMA A/B frag
typedef __attribute__((ext_vector_type(4))) float ffrag;   // 4 x f32 MFMA C/D frag
typedef __attribute__((ext_vector_type(4))) u32 u32x4;

__device__ __forceinline__ float bf2f(u16 h) { u32 v = ((u32)h) << 16; return __builtin_bit_cast(float, v); }
__device__ __forceinline__ u16 f2bf_bits(float f) {
  u32 x = __builtin_bit_cast(u32, f);
  x += 0x7FFFu + ((x >> 16) & 1u);   // round-to-nearest-even
  return (u16)(x >> 16);
}
// RNE pack via v_cvt_pk_bf16_f32.  a -> low 16, b -> high 16.
__device__ __forceinline__ u32 pack2f(float a, float b) {
  __hip_bfloat162 h = __float22bfloat162_rn(float2{a, b});
  u32 r;
  __builtin_memcpy(&r, &h, 4);
  return r;
}
__device__ __forceinline__ float fast_exp2(float x) {
#if __has_builtin(__builtin_amdgcn_exp2f)
  return __builtin_amdgcn_exp2f(x);          // v_exp_f32 (inputs bounded, no denorm)
#else
  return __expf(x * 0.6931471805599453f);
#endif
}

// ---------------------------------------------------------------------------
// Kernel 1: QKV GEMM (MFMA), BK=32 + T14 prefetch (reg-staged).  (unchanged
// from R12 — measured-best structure)
// ---------------------------------------------------------------------------
__global__ __launch_bounds__(256) void qkv_gemm(const u16* __restrict__ Xb,
                                                const u16* __restrict__ Wqb,
                                                u16* __restrict__ qb,
                                                u16* __restrict__ kb,
                                                u16* __restrict__ vb) {
  __shared__ u16 As[128][40];
  __shared__ u16 Bs[128][40];
  const int tid = threadIdx.x;
  const int lane = tid & 63;
  const int w = tid >> 6;
  const int wr = w >> 1, wc = w & 1;
  const int lrow = lane & 15, quad = lane >> 4;
  const int bm0 = blockIdx.x * 128;
  const int bn0 = blockIdx.y * 128;
  const int lr = tid >> 1;
  const int lc = (tid & 1) * 16;

  ffrag acc[4][4];
#pragma unroll
  for (int i = 0; i < 4; i++)
#pragma unroll
    for (int j = 0; j < 4; j++) acc[i][j] = (ffrag){0.f, 0.f, 0.f, 0.f};

  const u16* arow = Xb + (bm0 + lr) * 512 + lc;
  const u16* brow = Wqb + (bn0 + lr) * 512 + lc;
  uint4 a0 = ((const uint4*)arow)[0], a1 = ((const uint4*)arow)[1];
  uint4 b0 = ((const uint4*)brow)[0], b1 = ((const uint4*)brow)[1];

  for (int k0 = 0; k0 < 512; k0 += 32) {
    __syncthreads();
    *(uint4*)(&As[lr][lc])     = a0;
    *(uint4*)(&As[lr][lc + 8]) = a1;
    *(uint4*)(&Bs[lr][lc])     = b0;
    *(uint4*)(&Bs[lr][lc + 8]) = b1;
    __syncthreads();
    if (k0 + 32 < 512) {   // issue next tile NOW; completes under the MFMAs
      const uint4* apn = (const uint4*)(arow + k0 + 32);
      const uint4* bpn = (const uint4*)(brow + k0 + 32);
      a0 = apn[0]; a1 = apn[1];
      b0 = bpn[0]; b1 = bpn[1];
    }
    bfrag af[4], bf[4];
#pragma unroll
    for (int i = 0; i < 4; i++) af[i] = *(const bfrag*)(&As[wr * 64 + i * 16 + lrow][quad * 8]);
#pragma unroll
    for (int j = 0; j < 4; j++) bf[j] = *(const bfrag*)(&Bs[wc * 64 + j * 16 + lrow][quad * 8]);
#pragma unroll
    for (int i = 0; i < 4; i++)
#pragma unroll
      for (int j = 0; j < 4; j++)
        acc[i][j] = __builtin_amdgcn_mfma_f32_16x16x32_bf16(af[i], bf[j], acc[i][j], 0, 0, 0);
  }

#pragma unroll
  for (int i = 0; i < 4; i++)
#pragma unroll
    for (int j = 0; j < 4; j++) {
      int jj = bn0 + wc * 64 + j * 16 + lrow;            // 0..1535
      int which = jj >> 9, rem = jj & 511;
      int h = rem >> 5, d = rem & 31;
      u16* dst = (which == 0) ? qb : (which == 1) ? kb : vb;
#pragma unroll
      for (int r = 0; r < 4; r++) {
        int m = bm0 + wr * 64 + i * 16 + quad * 4 + r;   // 0..8191
        int pair = ((m >> 10) << 4) + h;
        int n = m & 1023;
        dst[(pair * 1024 + n) * 32 + d] = f2bf_bits(acc[i][j][r]);
      }
    }
}

// ---------------------------------------------------------------------------
// Kernel 2: LePE 5x5 depthwise conv + X->bf16 emit + FUSED weight convert.
// (unchanged from R12)
// ---------------------------------------------------------------------------
__global__ __launch_bounds__(256) void lepe_conv(const float* __restrict__ X,
                                                 const float* __restrict__ Wl,
                                                 const float* __restrict__ bl,
                                                 const float* __restrict__ Wq,
                                                 const float* __restrict__ Wp,
                                                 u16* __restrict__ out,
                                                 u16* __restrict__ xb,
                                                 u16* __restrict__ wqb,
                                                 u16* __restrict__ wpb) {
  if (blockIdx.z == 2) {
    // ---- weight conversion slice: 256 blocks x 256 thr x 4 float4 ----
    const int t = (blockIdx.y * 32 + blockIdx.x) * 256 + threadIdx.x;  // 0..65535
    const int NQ = 196608;    // 1536*512/4
#pragma unroll
    for (int k = 0; k < 4; k++) {
      int idx = t + k * 65536;                // 0..262143
      const float* src;
      u16* dst;
      int off;
      if (idx < NQ) { src = Wq; dst = wqb; off = idx; }
      else          { src = Wp; dst = wpb; off = idx - NQ; }
      float4 v = ((const float4*)src)[off];
      uint2 r;
      r.x = pack2f(v.x, v.y);
      r.y = pack2f(v.z, v.w);
      ((uint2*)dst)[off] = r;
    }
    return;
  }

  __shared__ float Wls[512 * 25];          // 51.2 KB, whole weight table
  const int tid = threadIdx.x;
  const int c = tid * 2;
  const int y = blockIdx.x;                // 0..31
  const int b = blockIdx.y;                // 0..7
  const int x0 = blockIdx.z * 16;          // 0 or 16

  {
    const float2* src = (const float2*)Wl;
    float2* dst = (float2*)Wls;
#pragma unroll
    for (int i = 0; i < 25; i++) dst[tid + i * 256] = src[tid + i * 256];
  }
  __syncthreads();

  float w0[25], w1[25];
#pragma unroll
  for (int t = 0; t < 25; t++) {
    w0[t] = Wls[c * 25 + t];
    w1[t] = Wls[(c + 1) * 25 + t];
  }
  const float2 bias = *(const float2*)(bl + c);

  const float* rowp[5];
  bool rowv[5];
#pragma unroll
  for (int r = 0; r < 5; r++) {
    int yy = y + r - 2;
    rowv[r] = (yy >= 0) && (yy < 32);
    rowp[r] = X + ((b * 32 + (rowv[r] ? yy : 0)) * 32) * 512 + c;
  }

  float2 win[5][5];
#pragma unroll
  for (int rel = -2; rel <= 1; rel++) {
    const int slot = ((rel % 5) + 5) % 5;
    const int xcol = x0 + rel;
    const bool xv = (xcol >= 0) && (xcol < 32);
#pragma unroll
    for (int r = 0; r < 5; r++)
      win[r][slot] = (xv && rowv[r]) ? *(const float2*)(rowp[r] + xcol * 512)
                                     : float2{0.f, 0.f};
  }

#pragma unroll
  for (int xi = 0; xi < 16; xi++) {
    {
      const int slot = (xi + 2) % 5;
      const int xcol = x0 + xi + 2;
      const bool xv = (xcol < 32);
#pragma unroll
      for (int r = 0; r < 5; r++)
        win[r][slot] = (xv && rowv[r]) ? *(const float2*)(rowp[r] + xcol * 512)
                                       : float2{0.f, 0.f};
    }
    float a0 = bias.x, a1 = bias.y;
#pragma unroll
    for (int ky = 0; ky < 5; ky++)
#pragma unroll
      for (int kx = 0; kx < 5; kx++) {
        const int rel = xi - 2 + kx;
        const int slot = ((rel % 5) + 5) % 5;
        const float2 v = win[ky][slot];
        const int t = ky * 5 + kx;
        a0 = fmaf(v.x, w0[t], a0);
        a1 = fmaf(v.y, w1[t], a1);
      }
    const int sp = (b * 32 + y) * 32 + x0 + xi;
    *(u32*)(out + sp * 512 + c) = pack2f(a0, a1);
    const float2 ctr = win[2][xi % 5];     // X at (y, x0+xi), channels c,c+1
    *(u32*)(xb + sp * 512 + c) = pack2f(ctr.x, ctr.y);
  }
}

// ---------------------------------------------------------------------------
// Kernel 3: MFMA flash attention, v9 — cross-step software pipeline.
//  v7 exposed the QK->exp MFMA-result latency serially every step.  v9
//  carries s one step: each body issues QK(n+1), then exp(n)/PV(n) run UNDER
//  those in-flight MFMAs.  K-ring 2 deep (kfA = step n+1's keys, kfB = n+2).
//  Chunk prologue computes its step 0 (total QK count unchanged).  +16 VGPR
//  (second s set) — est ~120, under the (512,4) 128-VGPR cap.  Math identical.
// ---------------------------------------------------------------------------
__global__ __launch_bounds__(512, 4) void attn_mfma(const u16* __restrict__ qb,
                                                    const u16* __restrict__ kb,
                                                    const u16* __restrict__ vb,
                                                    const u16* __restrict__ lp,
                                                    u16* __restrict__ ao) {
  __shared__ u32 Vt[32][132];    // 16.9 KB  V^T chunk: [d][keypair(g*16+t)] = (v[j]|v[j+16]<<16)
  const int tid = threadIdx.x, lane = tid & 63, w = tid >> 6;   // w 0..7
  const int quad = lane >> 4, m16 = lane & 15;
  const int pair = blockIdx.x >> 2;
  const int quarter = blockIdx.x & 3;
  const int b = pair >> 4, h = pair & 15;

  // ---- per-wave Q fragments (32 rows: 2 tiles of 16) ----
  const int wq0 = quarter * 256 + w * 32;
  bfrag qf[2];
#pragma unroll
  for (int i = 0; i < 2; i++) {
    int row = wq0 + i * 16 + m16;
    qf[i] = *(const bfrag*)(qb + (pair * 1024 + row) * 32 + quad * 8);
  }

  // scale/shift folded for exp2: p = 2^(s * SC2 - SHIFT2) = e^(s/sqrt(32) - 8)
  const float SC2 = 0.25503448540239605f;      // log2(e)/sqrt(32)
  const float SHIFT2 = 11.541560327111707f;    // 8*log2(e)
  const u16* kbase = kb + pair * 32768;
  const u16* vbase = vb + pair * 32768;

  bfrag onesf;
#pragma unroll
  for (int e = 0; e < 8; e++) onesf[e] = (short)0x3F80;   // bf16 1.0

  ffrag oacc[2][2], sacc[2];
#pragma unroll
  for (int i = 0; i < 2; i++) {
    oacc[i][0] = (ffrag){0.f, 0.f, 0.f, 0.f};
    oacc[i][1] = (ffrag){0.f, 0.f, 0.f, 0.f};
    sacc[i]    = (ffrag){0.f, 0.f, 0.f, 0.f};
  }

  // ---- V-staging thread geometry (constant per thread) ----
  const int pp = tid & 127;            // keypair col = g*16 + t
  const int vq = tid >> 7;             // 16B quarter of the 64B value rows
  const int vg = pp >> 4, vt = pp & 15;
  const int jbase = vg * 32 + vt;
  // prologue: chunk 0 V loads (complete while we wait at first barrier)
  uint4 svl = *(const uint4*)(vbase + jbase * 32 + vq * 8);
  uint4 svh = *(const uint4*)(vbase + (jbase + 16) * 32 + vq * 8);

  // K ring, 2 steps deep.  Invariant at each QK site for step n:
  //   kfA = keys of step n, kfB = keys of step n+1.
  // Over-reads for the last pair land <= ~8 KB into vb (allocated), unused.
  bfrag kfA0 = *(const bfrag*)(kbase + (m16) * 32 + quad * 8);
  bfrag kfA1 = *(const bfrag*)(kbase + (16 + m16) * 32 + quad * 8);
  bfrag kfB0 = *(const bfrag*)(kbase + (32 + m16) * 32 + quad * 8);
  bfrag kfB1 = *(const bfrag*)(kbase + (48 + m16) * 32 + quad * 8);

  for (int jc = 0; jc < 1024; jc += 256) {
    // ---- stage V^T chunk from pre-loaded regs (LDS writes only) ----
    __syncthreads();                 // previous chunk's vf reads complete
    {
      u32 lw[4] = {svl.x, svl.y, svl.z, svl.w};
      u32 hw[4] = {svh.x, svh.y, svh.z, svh.w};
#pragma unroll
      for (int e = 0; e < 4; e++) {
        int d0 = vq * 8 + e * 2;
        Vt[d0][pp]     = (lw[e] & 0xFFFFu) | (hw[e] << 16);
        Vt[d0 + 1][pp] = (lw[e] >> 16) | (hw[e] & 0xFFFF0000u);
      }
    }
    __syncthreads();
    if (jc + 256 < 1024) {           // issue next chunk's loads; they land
      int jlo = jc + 256 + jbase;    // during the inner compute loop
      svl = *(const uint4*)(vbase + jlo * 32 + vq * 8);
      svh = *(const uint4*)(vbase + (jlo + 16) * 32 + vq * 8);
    }

    // ---- chunk prologue: QK for local step 0 (keys jc..jc+31) ----
    ffrag scur[2][2];
    __builtin_amdgcn_s_setprio(1);
#pragma unroll
    for (int i = 0; i < 2; i++) {
      scur[i][0] = __builtin_amdgcn_mfma_f32_16x16x32_bf16(kfA0, qf[i], (ffrag){0.f,0.f,0.f,0.f}, 0, 0, 0);
      scur[i][1] = __builtin_amdgcn_mfma_f32_16x16x32_bf16(kfA1, qf[i], (ffrag){0.f,0.f,0.f,0.f}, 0, 0, 0);
    }
    __builtin_amdgcn_s_setprio(0);
    // ring advance: kfA <- keys jc+32, kfB <- keys jc+64
    kfA0 = kfB0; kfA1 = kfB1;
    {
      const int jn = jc + 64;
      kfB0 = *(const bfrag*)(kbase + (jn + m16) * 32 + quad * 8);
      kfB1 = *(const bfrag*)(kbase + (jn + 16 + m16) * 32 + quad * 8);
    }

#pragma unroll
    for (int j0 = 0; j0 < 256; j0 += 32) {
      const int g0 = j0 >> 5;
      bfrag vf0 = *(const bfrag*)(&Vt[m16][g0 * 16 + quad * 4]);
      bfrag vf1 = *(const bfrag*)(&Vt[16 + m16][g0 * 16 + quad * 4]);

      // --- issue NEXT step's QK MFMAs (exp/PV below run under them) ---
      ffrag snxt[2][2];
      const bool haveNext = (j0 + 32 < 256);
      if (haveNext) {
        __builtin_amdgcn_s_setprio(1);
#pragma unroll
        for (int i = 0; i < 2; i++) {
          snxt[i][0] = __builtin_amdgcn_mfma_f32_16x16x32_bf16(kfA0, qf[i], (ffrag){0.f,0.f,0.f,0.f}, 0, 0, 0);
          snxt[i][1] = __builtin_amdgcn_mfma_f32_16x16x32_bf16(kfA1, qf[i], (ffrag){0.f,0.f,0.f,0.f}, 0, 0, 0);
        }
        __builtin_amdgcn_s_setprio(0);
        kfA0 = kfB0; kfA1 = kfB1;
        const int jn = jc + j0 + 96;   // keys for step n+2
        kfB0 = *(const bfrag*)(kbase + (jn + m16) * 32 + quad * 8);
        kfB1 = *(const bfrag*)(kbase + (jn + 16 + m16) * 32 + quad * 8);
      }

      // --- exp(scur) -> pa (overlaps snxt QK MFMAs in the matrix pipe) ---
      bfrag pa[2];
#pragma unroll
      for (int i = 0; i < 2; i++) {
        u32x4 paw;
#pragma unroll
        for (int r = 0; r < 4; r++) {
          float p0 = fast_exp2(fmaf(scur[i][0][r], SC2, -SHIFT2));   // key g=0 (lo)
          float p1 = fast_exp2(fmaf(scur[i][1][r], SC2, -SHIFT2));   // key g=1 (hi)
          paw[r] = pack2f(p0, p1);                                   // A-frag u32 c=r
        }
        pa[i] = __builtin_bit_cast(bfrag, paw);
      }

      // --- row-sum + PV MFMAs for step n ---
      __builtin_amdgcn_s_setprio(1);
#pragma unroll
      for (int i = 0; i < 2; i++) {
        sacc[i]    = __builtin_amdgcn_mfma_f32_16x16x32_bf16(pa[i], onesf, sacc[i], 0, 0, 0);
        oacc[i][0] = __builtin_amdgcn_mfma_f32_16x16x32_bf16(pa[i], vf0, oacc[i][0], 0, 0, 0);
        oacc[i][1] = __builtin_amdgcn_mfma_f32_16x16x32_bf16(pa[i], vf1, oacc[i][1], 0, 0, 0);
      }
      __builtin_amdgcn_s_setprio(0);

      if (haveNext) {
#pragma unroll
        for (int i = 0; i < 2; i++) {
          scur[i][0] = snxt[i][0];
          scur[i][1] = snxt[i][1];
        }
      }
    }
  }

  // ---- epilogue: l from sacc (shuffle-free), normalize, +LePE, store ----
#pragma unroll
  for (int i = 0; i < 2; i++) {
    float inv[4];
#pragma unroll
    for (int r = 0; r < 4; r++) inv[r] = 1.0f / sacc[i][r];
#pragma unroll
    for (int jd = 0; jd < 2; jd++)
#pragma unroll
      for (int r = 0; r < 4; r++) {
        int row = wq0 + i * 16 + quad * 4 + r;
        int col = jd * 16 + m16;
        int o = (b * 1024 + row) * 512 + h * 32 + col;
        float val = fmaf(oacc[i][jd][r], inv[r], bf2f(lp[o]));
        ao[o] = f2bf_bits(val);
      }
  }
}

// ---------------------------------------------------------------------------
// Kernel 4: proj GEMM (MFMA), BK=32 + T14 prefetch, BM=128 x BN=64.
// (unchanged from R12)
// ---------------------------------------------------------------------------
__global__ __launch_bounds__(256) void proj_gemm(const u16* __restrict__ Y,
                                                 const u16* __restrict__ Wpb,
                                                 const float* __restrict__ bp,
                                                 float* __restrict__ out) {
  __shared__ u16 As[128][40];
  __shared__ u16 Bs[64][40];
  const int tid = threadIdx.x;
  const int lane = tid & 63;
  const int w = tid >> 6;
  const int wr = w >> 1, wc = w & 1;
  const int lrow = lane & 15, quad = lane >> 4;
  const int bm0 = blockIdx.x * 128;
  const int bn0 = blockIdx.y * 64;
  const int lr = tid >> 1;
  const int lc = (tid & 1) * 16;
  const int br = tid >> 2;          // 0..63
  const int bc = (tid & 3) * 8;     // 0,8,16,24

  ffrag acc[4][2];
#pragma unroll
  for (int i = 0; i < 4; i++)
#pragma unroll
    for (int j = 0; j < 2; j++) acc[i][j] = (ffrag){0.f, 0.f, 0.f, 0.f};

  const u16* arow = Y + (bm0 + lr) * 512 + lc;
  const u16* brow = Wpb + (bn0 + br) * 512 + bc;
  uint4 a0 = ((const uint4*)arow)[0], a1 = ((const uint4*)arow)[1];
  uint4 b0 = *(const uint4*)brow;

  for (int k0 = 0; k0 < 512; k0 += 32) {
    __syncthreads();
    *(uint4*)(&As[lr][lc])     = a0;
    *(uint4*)(&As[lr][lc + 8]) = a1;
    *(uint4*)(&Bs[br][bc])     = b0;
    __syncthreads();
    if (k0 + 32 < 512) {
      const uint4* apn = (const uint4*)(arow + k0 + 32);
      a0 = apn[0]; a1 = apn[1];
      b0 = *(const uint4*)(brow + k0 + 32);
    }
    bfrag af[4], bf[2];
#pragma unroll
    for (int i = 0; i < 4; i++) af[i] = *(const bfrag*)(&As[wr * 64 + i * 16 + lrow][quad * 8]);
#pragma unroll
    for (int j = 0; j < 2; j++) bf[j] = *(const bfrag*)(&Bs[wc * 32 + j * 16 + lrow][quad * 8]);
#pragma unroll
    for (int i = 0; i < 4; i++)
#pragma unroll
      for (int j = 0; j < 2; j++)
        acc[i][j] = __builtin_amdgcn_mfma_f32_16x16x32_bf16(af[i], bf[j], acc[i][j], 0, 0, 0);
  }

#pragma unroll
  for (int i = 0; i < 4; i++)
#pragma unroll
    for (int j = 0; j < 2; j++) {
      int jj = bn0 + wc * 32 + j * 16 + lrow;     // 0..511
      float bias = bp[jj];
#pragma unroll
      for (int r = 0; r < 4; r++) {
        int m = bm0 + wr * 64 + i * 16 + quad * 4 + r;
        out[m * 512 + jj] = acc[i][j][r] + bias;   // FP32 output
      }
    }
}

// ---------------------------------------------------------------------------
extern "C" void kernel_launch(void* const* d_in, const int* in_sizes, int n_in,
                              void* d_out, int out_size, void* d_ws, size_t ws_size,
                              hipStream_t stream) {
  const float* x      = (const float*)d_in[0];
  const float* w_qkv  = (const float*)d_in[1];
  const float* w_proj = (const float*)d_in[2];
  const float* b_proj = (const float*)d_in[3];
  const float* w_lepe = (const float*)d_in[4];
  const float* b_lepe = (const float*)d_in[5];
  float* out = (float*)d_out;                  // reference output dtype = float32

  char* ws = (char*)d_ws;
  const size_t SEG = 8388608;                  // 8192*512*2 bytes (bf16)
  u16* qb  = (u16*)(ws + 0 * SEG);
  u16* kb  = (u16*)(ws + 1 * SEG);
  u16* vb  = (u16*)(ws + 2 * SEG);
  u16* ao  = (u16*)(ws + 3 * SEG);
  u16* lp  = (u16*)(ws + 4 * SEG);
  u16* xb  = (u16*)(ws + 5 * SEG);             // 8192*512 bf16 (written by lepe)
  u16* wqb = (u16*)(ws + 6 * SEG);             // 1536*512 bf16 (1.5 MB)
  u16* wpb = (u16*)(ws + 6 * SEG + 1572864);   // 512*512 bf16 (0.5 MB)

  // lepe grid z: 0,1 = conv halves; 2 = fused weight conversion slice
  hipLaunchKernelGGL(lepe_conv, dim3(32, 8, 3), dim3(256), 0, stream,
                     x, w_lepe, b_lepe, w_qkv, w_proj, lp, xb, wqb, wpb);
  hipLaunchKernelGGL(qkv_gemm, dim3(64, 12), dim3(256), 0, stream, xb, wqb, qb, kb, vb);
  hipLaunchKernelGGL(attn_mfma, dim3(512), dim3(512), 0, stream, qb, kb, vb, lp, ao);
  hipLaunchKernelGGL(proj_gemm, dim3(64, 8), dim3(256), 0, stream, ao, wpb, b_proj, out);
}

// Round 14
// 155.507 us; speedup vs baseline: 1.0330x; 1.0330x over previous
//
#include <hip/hip_runtime.h>
#include <hip/hip_bf16.h>

typedef unsigned int u32;
typedef unsigned short u16;
typedef __attribute__((ext_vector_type(8))) short bfrag;   // 8 x bf16 MFMA A/B frag
typedef __attribute__((ext_vector_type(4))) float ffrag;   // 4 x f32 MFMA C/D frag
typedef __attribute__((ext_vector_type(4))) u32 u32x4;

__device__ __forceinline__ float bf2f(u16 h) { u32 v = ((u32)h) << 16; return __builtin_bit_cast(float, v); }
__device__ __forceinline__ u16 f2bf_bits(float f) {
  u32 x = __builtin_bit_cast(u32, f);
  x += 0x7FFFu + ((x >> 16) & 1u);   // round-to-nearest-even
  return (u16)(x >> 16);
}
// RNE pack via v_cvt_pk_bf16_f32.  a -> low 16, b -> high 16.
__device__ __forceinline__ u32 pack2f(float a, float b) {
  __hip_bfloat162 h = __float22bfloat162_rn(float2{a, b});
  u32 r;
  __builtin_memcpy(&r, &h, 4);
  return r;
}
__device__ __forceinline__ float fast_exp2(float x) {
#if __has_builtin(__builtin_amdgcn_exp2f)
  return __builtin_amdgcn_exp2f(x);          // v_exp_f32 (inputs bounded, no denorm)
#else
  return __expf(x * 0.6931471805599453f);
#endif
}

// ---------------------------------------------------------------------------
// Kernel 1: QKV GEMM (MFMA), BK=32 + T14 prefetch (reg-staged).
//  Measured-best structure (R10: 158.19 us total; R12 re-verify: 158.98).
//  Probed and rejected: BK=64 (R9, -6.6us), gload_lds fragment-major (R11,
//  -11.4us: per-lane 1KB-strided scatter multiplies L2 transactions).
// ---------------------------------------------------------------------------
__global__ __launch_bounds__(256) void qkv_gemm(const u16* __restrict__ Xb,
                                                const u16* __restrict__ Wqb,
                                                u16* __restrict__ qb,
                                                u16* __restrict__ kb,
                                                u16* __restrict__ vb) {
  __shared__ u16 As[128][40];
  __shared__ u16 Bs[128][40];
  const int tid = threadIdx.x;
  const int lane = tid & 63;
  const int w = tid >> 6;
  const int wr = w >> 1, wc = w & 1;
  const int lrow = lane & 15, quad = lane >> 4;
  const int bm0 = blockIdx.x * 128;
  const int bn0 = blockIdx.y * 128;
  const int lr = tid >> 1;
  const int lc = (tid & 1) * 16;

  ffrag acc[4][4];
#pragma unroll
  for (int i = 0; i < 4; i++)
#pragma unroll
    for (int j = 0; j < 4; j++) acc[i][j] = (ffrag){0.f, 0.f, 0.f, 0.f};

  const u16* arow = Xb + (bm0 + lr) * 512 + lc;
  const u16* brow = Wqb + (bn0 + lr) * 512 + lc;
  uint4 a0 = ((const uint4*)arow)[0], a1 = ((const uint4*)arow)[1];
  uint4 b0 = ((const uint4*)brow)[0], b1 = ((const uint4*)brow)[1];

  for (int k0 = 0; k0 < 512; k0 += 32) {
    __syncthreads();
    *(uint4*)(&As[lr][lc])     = a0;
    *(uint4*)(&As[lr][lc + 8]) = a1;
    *(uint4*)(&Bs[lr][lc])     = b0;
    *(uint4*)(&Bs[lr][lc + 8]) = b1;
    __syncthreads();
    if (k0 + 32 < 512) {   // issue next tile NOW; completes under the MFMAs
      const uint4* apn = (const uint4*)(arow + k0 + 32);
      const uint4* bpn = (const uint4*)(brow + k0 + 32);
      a0 = apn[0]; a1 = apn[1];
      b0 = bpn[0]; b1 = bpn[1];
    }
    bfrag af[4], bf[4];
#pragma unroll
    for (int i = 0; i < 4; i++) af[i] = *(const bfrag*)(&As[wr * 64 + i * 16 + lrow][quad * 8]);
#pragma unroll
    for (int j = 0; j < 4; j++) bf[j] = *(const bfrag*)(&Bs[wc * 64 + j * 16 + lrow][quad * 8]);
#pragma unroll
    for (int i = 0; i < 4; i++)
#pragma unroll
      for (int j = 0; j < 4; j++)
        acc[i][j] = __builtin_amdgcn_mfma_f32_16x16x32_bf16(af[i], bf[j], acc[i][j], 0, 0, 0);
  }

#pragma unroll
  for (int i = 0; i < 4; i++)
#pragma unroll
    for (int j = 0; j < 4; j++) {
      int jj = bn0 + wc * 64 + j * 16 + lrow;            // 0..1535
      int which = jj >> 9, rem = jj & 511;
      int h = rem >> 5, d = rem & 31;
      u16* dst = (which == 0) ? qb : (which == 1) ? kb : vb;
#pragma unroll
      for (int r = 0; r < 4; r++) {
        int m = bm0 + wr * 64 + i * 16 + quad * 4 + r;   // 0..8191
        int pair = ((m >> 10) << 4) + h;
        int n = m & 1023;
        dst[(pair * 1024 + n) * 32 + d] = f2bf_bits(acc[i][j][r]);
      }
    }
}

// ---------------------------------------------------------------------------
// Kernel 2: LePE 5x5 depthwise conv + X->bf16 emit + FUSED weight convert.
// ---------------------------------------------------------------------------
__global__ __launch_bounds__(256) void lepe_conv(const float* __restrict__ X,
                                                 const float* __restrict__ Wl,
                                                 const float* __restrict__ bl,
                                                 const float* __restrict__ Wq,
                                                 const float* __restrict__ Wp,
                                                 u16* __restrict__ out,
                                                 u16* __restrict__ xb,
                                                 u16* __restrict__ wqb,
                                                 u16* __restrict__ wpb) {
  if (blockIdx.z == 2) {
    // ---- weight conversion slice: 256 blocks x 256 thr x 4 float4 ----
    const int t = (blockIdx.y * 32 + blockIdx.x) * 256 + threadIdx.x;  // 0..65535
    const int NQ = 196608;    // 1536*512/4
#pragma unroll
    for (int k = 0; k < 4; k++) {
      int idx = t + k * 65536;                // 0..262143
      const float* src;
      u16* dst;
      int off;
      if (idx < NQ) { src = Wq; dst = wqb; off = idx; }
      else          { src = Wp; dst = wpb; off = idx - NQ; }
      float4 v = ((const float4*)src)[off];
      uint2 r;
      r.x = pack2f(v.x, v.y);
      r.y = pack2f(v.z, v.w);
      ((uint2*)dst)[off] = r;
    }
    return;
  }

  __shared__ float Wls[512 * 25];          // 51.2 KB, whole weight table
  const int tid = threadIdx.x;
  const int c = tid * 2;
  const int y = blockIdx.x;                // 0..31
  const int b = blockIdx.y;                // 0..7
  const int x0 = blockIdx.z * 16;          // 0 or 16

  {
    const float2* src = (const float2*)Wl;
    float2* dst = (float2*)Wls;
#pragma unroll
    for (int i = 0; i < 25; i++) dst[tid + i * 256] = src[tid + i * 256];
  }
  __syncthreads();

  float w0[25], w1[25];
#pragma unroll
  for (int t = 0; t < 25; t++) {
    w0[t] = Wls[c * 25 + t];
    w1[t] = Wls[(c + 1) * 25 + t];
  }
  const float2 bias = *(const float2*)(bl + c);

  const float* rowp[5];
  bool rowv[5];
#pragma unroll
  for (int r = 0; r < 5; r++) {
    int yy = y + r - 2;
    rowv[r] = (yy >= 0) && (yy < 32);
    rowp[r] = X + ((b * 32 + (rowv[r] ? yy : 0)) * 32) * 512 + c;
  }

  float2 win[5][5];
#pragma unroll
  for (int rel = -2; rel <= 1; rel++) {
    const int slot = ((rel % 5) + 5) % 5;
    const int xcol = x0 + rel;
    const bool xv = (xcol >= 0) && (xcol < 32);
#pragma unroll
    for (int r = 0; r < 5; r++)
      win[r][slot] = (xv && rowv[r]) ? *(const float2*)(rowp[r] + xcol * 512)
                                     : float2{0.f, 0.f};
  }

#pragma unroll
  for (int xi = 0; xi < 16; xi++) {
    {
      const int slot = (xi + 2) % 5;
      const int xcol = x0 + xi + 2;
      const bool xv = (xcol < 32);
#pragma unroll
      for (int r = 0; r < 5; r++)
        win[r][slot] = (xv && rowv[r]) ? *(const float2*)(rowp[r] + xcol * 512)
                                       : float2{0.f, 0.f};
    }
    float a0 = bias.x, a1 = bias.y;
#pragma unroll
    for (int ky = 0; ky < 5; ky++)
#pragma unroll
      for (int kx = 0; kx < 5; kx++) {
        const int rel = xi - 2 + kx;
        const int slot = ((rel % 5) + 5) % 5;
        const float2 v = win[ky][slot];
        const int t = ky * 5 + kx;
        a0 = fmaf(v.x, w0[t], a0);
        a1 = fmaf(v.y, w1[t], a1);
      }
    const int sp = (b * 32 + y) * 32 + x0 + xi;
    *(u32*)(out + sp * 512 + c) = pack2f(a0, a1);
    const float2 ctr = win[2][xi % 5];     // X at (y, x0+xi), channels c,c+1
    *(u32*)(xb + sp * 512 + c) = pack2f(ctr.x, ctr.y);
  }
}

// ---------------------------------------------------------------------------
// Kernel 3: MFMA flash attention, v7 (zero-shuffle P, clustered schedule).
//  Final form.  Probed and rejected: per-i serialized schedule (v6, R7),
//  j-unroll x2 (v8/R9, VGPR cap), cross-step pipeline (v9/R13, 160.6us).
// ---------------------------------------------------------------------------
__global__ __launch_bounds__(512, 4) void attn_mfma(const u16* __restrict__ qb,
                                                    const u16* __restrict__ kb,
                                                    const u16* __restrict__ vb,
                                                    const u16* __restrict__ lp,
                                                    u16* __restrict__ ao) {
  __shared__ u32 Vt[32][132];    // 16.9 KB  V^T chunk: [d][keypair(g*16+t)] = (v[j]|v[j+16]<<16)
  const int tid = threadIdx.x, lane = tid & 63, w = tid >> 6;   // w 0..7
  const int quad = lane >> 4, m16 = lane & 15;
  const int pair = blockIdx.x >> 2;
  const int quarter = blockIdx.x & 3;
  const int b = pair >> 4, h = pair & 15;

  // ---- per-wave Q fragments (32 rows: 2 tiles of 16) ----
  const int wq0 = quarter * 256 + w * 32;
  bfrag qf[2];
#pragma unroll
  for (int i = 0; i < 2; i++) {
    int row = wq0 + i * 16 + m16;
    qf[i] = *(const bfrag*)(qb + (pair * 1024 + row) * 32 + quad * 8);
  }

  // scale/shift folded for exp2: p = 2^(s * SC2 - SHIFT2) = e^(s/sqrt(32) - 8)
  const float SC2 = 0.25503448540239605f;      // log2(e)/sqrt(32)
  const float SHIFT2 = 11.541560327111707f;    // 8*log2(e)
  const u16* kbase = kb + pair * 32768;
  const u16* vbase = vb + pair * 32768;

  bfrag onesf;
#pragma unroll
  for (int e = 0; e < 8; e++) onesf[e] = (short)0x3F80;   // bf16 1.0

  ffrag oacc[2][2], sacc[2];
#pragma unroll
  for (int i = 0; i < 2; i++) {
    oacc[i][0] = (ffrag){0.f, 0.f, 0.f, 0.f};
    oacc[i][1] = (ffrag){0.f, 0.f, 0.f, 0.f};
    sacc[i]    = (ffrag){0.f, 0.f, 0.f, 0.f};
  }

  // ---- V-staging thread geometry (constant per thread) ----
  const int pp = tid & 127;            // keypair col = g*16 + t
  const int vq = tid >> 7;             // 16B quarter of the 64B value rows
  const int vg = pp >> 4, vt = pp & 15;
  const int jbase = vg * 32 + vt;
  // prologue: chunk 0 V loads (complete while we wait at first barrier)
  uint4 svl = *(const uint4*)(vbase + jbase * 32 + vq * 8);
  uint4 svh = *(const uint4*)(vbase + (jbase + 16) * 32 + vq * 8);

  // K prefetch (j-step ahead; final iteration over-read lands in vb, unused)
  bfrag kf0n = *(const bfrag*)(kbase + (m16) * 32 + quad * 8);
  bfrag kf1n = *(const bfrag*)(kbase + (16 + m16) * 32 + quad * 8);

  for (int jc = 0; jc < 1024; jc += 256) {
    // ---- stage V^T chunk from pre-loaded regs (LDS writes only) ----
    __syncthreads();                 // previous chunk's vf reads complete
    {
      u32 lw[4] = {svl.x, svl.y, svl.z, svl.w};
      u32 hw[4] = {svh.x, svh.y, svh.z, svh.w};
#pragma unroll
      for (int e = 0; e < 4; e++) {
        int d0 = vq * 8 + e * 2;
        Vt[d0][pp]     = (lw[e] & 0xFFFFu) | (hw[e] << 16);
        Vt[d0 + 1][pp] = (lw[e] >> 16) | (hw[e] & 0xFFFF0000u);
      }
    }
    __syncthreads();
    if (jc + 256 < 1024) {           // issue next chunk's loads; they land
      int jlo = jc + 256 + jbase;    // during the inner compute loop
      svl = *(const uint4*)(vbase + jlo * 32 + vq * 8);
      svh = *(const uint4*)(vbase + (jlo + 16) * 32 + vq * 8);
    }

    for (int j0 = 0; j0 < 256; j0 += 32) {
      const int g0 = j0 >> 5;
      bfrag kf0 = kf0n, kf1 = kf1n;
      {
        const int jn = jc + j0 + 32;   // may run 1 step past kb end for pair 127: lands in vb, unused
        kf0n = *(const bfrag*)(kbase + (jn + m16) * 32 + quad * 8);
        kf1n = *(const bfrag*)(kbase + (jn + 16 + m16) * 32 + quad * 8);
      }
      bfrag vf0 = *(const bfrag*)(&Vt[m16][g0 * 16 + quad * 4]);
      bfrag vf1 = *(const bfrag*)(&Vt[16 + m16][g0 * 16 + quad * 4]);

      // --- cluster 1: all 4 QK^T MFMAs (independent) ---
      ffrag s[2][2];
      __builtin_amdgcn_s_setprio(1);
#pragma unroll
      for (int i = 0; i < 2; i++) {
        // swapped operands: D = K·Q^T; lane holds S[key jk+quad*4+r][q=m16]
        s[i][0] = __builtin_amdgcn_mfma_f32_16x16x32_bf16(kf0, qf[i], (ffrag){0.f,0.f,0.f,0.f}, 0, 0, 0);
        s[i][1] = __builtin_amdgcn_mfma_f32_16x16x32_bf16(kf1, qf[i], (ffrag){0.f,0.f,0.f,0.f}, 0, 0, 0);
      }
      __builtin_amdgcn_s_setprio(0);

      // --- cluster 2: 16 independent exps + 8 cvt_pk packs ---
      bfrag pa[2];
#pragma unroll
      for (int i = 0; i < 2; i++) {
        u32x4 paw;
#pragma unroll
        for (int r = 0; r < 4; r++) {
          float p0 = fast_exp2(fmaf(s[i][0][r], SC2, -SHIFT2));   // key g=0 (lo)
          float p1 = fast_exp2(fmaf(s[i][1][r], SC2, -SHIFT2));   // key g=1 (hi)
          paw[r] = pack2f(p0, p1);                                // A-frag u32 c=r
        }
        pa[i] = __builtin_bit_cast(bfrag, paw);
      }

      // --- cluster 3: 2 row-sum + 4 PV MFMAs ---
      __builtin_amdgcn_s_setprio(1);
#pragma unroll
      for (int i = 0; i < 2; i++) {
        sacc[i]    = __builtin_amdgcn_mfma_f32_16x16x32_bf16(pa[i], onesf, sacc[i], 0, 0, 0);
        oacc[i][0] = __builtin_amdgcn_mfma_f32_16x16x32_bf16(pa[i], vf0, oacc[i][0], 0, 0, 0);
        oacc[i][1] = __builtin_amdgcn_mfma_f32_16x16x32_bf16(pa[i], vf1, oacc[i][1], 0, 0, 0);
      }
      __builtin_amdgcn_s_setprio(0);
    }
  }

  // ---- epilogue: l from sacc (shuffle-free), normalize, +LePE, store ----
#pragma unroll
  for (int i = 0; i < 2; i++) {
    float inv[4];
#pragma unroll
    for (int r = 0; r < 4; r++) inv[r] = 1.0f / sacc[i][r];
#pragma unroll
    for (int jd = 0; jd < 2; jd++)
#pragma unroll
      for (int r = 0; r < 4; r++) {
        int row = wq0 + i * 16 + quad * 4 + r;
        int col = jd * 16 + m16;
        int o = (b * 1024 + row) * 512 + h * 32 + col;
        float val = fmaf(oacc[i][jd][r], inv[r], bf2f(lp[o]));
        ao[o] = f2bf_bits(val);
      }
  }
}

// ---------------------------------------------------------------------------
// Kernel 4: proj GEMM (MFMA), BK=32 + T14 prefetch, BM=128 x BN=64.
// ---------------------------------------------------------------------------
__global__ __launch_bounds__(256) void proj_gemm(const u16* __restrict__ Y,
                                                 const u16* __restrict__ Wpb,
                                                 const float* __restrict__ bp,
                                                 float* __restrict__ out) {
  __shared__ u16 As[128][40];
  __shared__ u16 Bs[64][40];
  const int tid = threadIdx.x;
  const int lane = tid & 63;
  const int w = tid >> 6;
  const int wr = w >> 1, wc = w & 1;
  const int lrow = lane & 15, quad = lane >> 4;
  const int bm0 = blockIdx.x * 128;
  const int bn0 = blockIdx.y * 64;
  const int lr = tid >> 1;
  const int lc = (tid & 1) * 16;
  const int br = tid >> 2;          // 0..63
  const int bc = (tid & 3) * 8;     // 0,8,16,24

  ffrag acc[4][2];
#pragma unroll
  for (int i = 0; i < 4; i++)
#pragma unroll
    for (int j = 0; j < 2; j++) acc[i][j] = (ffrag){0.f, 0.f, 0.f, 0.f};

  const u16* arow = Y + (bm0 + lr) * 512 + lc;
  const u16* brow = Wpb + (bn0 + br) * 512 + bc;
  uint4 a0 = ((const uint4*)arow)[0], a1 = ((const uint4*)arow)[1];
  uint4 b0 = *(const uint4*)brow;

  for (int k0 = 0; k0 < 512; k0 += 32) {
    __syncthreads();
    *(uint4*)(&As[lr][lc])     = a0;
    *(uint4*)(&As[lr][lc + 8]) = a1;
    *(uint4*)(&Bs[br][bc])     = b0;
    __syncthreads();
    if (k0 + 32 < 512) {
      const uint4* apn = (const uint4*)(arow + k0 + 32);
      a0 = apn[0]; a1 = apn[1];
      b0 = *(const uint4*)(brow + k0 + 32);
    }
    bfrag af[4], bf[2];
#pragma unroll
    for (int i = 0; i < 4; i++) af[i] = *(const bfrag*)(&As[wr * 64 + i * 16 + lrow][quad * 8]);
#pragma unroll
    for (int j = 0; j < 2; j++) bf[j] = *(const bfrag*)(&Bs[wc * 32 + j * 16 + lrow][quad * 8]);
#pragma unroll
    for (int i = 0; i < 4; i++)
#pragma unroll
      for (int j = 0; j < 2; j++)
        acc[i][j] = __builtin_amdgcn_mfma_f32_16x16x32_bf16(af[i], bf[j], acc[i][j], 0, 0, 0);
  }

#pragma unroll
  for (int i = 0; i < 4; i++)
#pragma unroll
    for (int j = 0; j < 2; j++) {
      int jj = bn0 + wc * 32 + j * 16 + lrow;     // 0..511
      float bias = bp[jj];
#pragma unroll
      for (int r = 0; r < 4; r++) {
        int m = bm0 + wr * 64 + i * 16 + quad * 4 + r;
        out[m * 512 + jj] = acc[i][j][r] + bias;   // FP32 output
      }
    }
}

// ---------------------------------------------------------------------------
extern "C" void kernel_launch(void* const* d_in, const int* in_sizes, int n_in,
                              void* d_out, int out_size, void* d_ws, size_t ws_size,
                              hipStream_t stream) {
  const float* x      = (const float*)d_in[0];
  const float* w_qkv  = (const float*)d_in[1];
  const float* w_proj = (const float*)d_in[2];
  const float* b_proj = (const float*)d_in[3];
  const float* w_lepe = (const float*)d_in[4];
  const float* b_lepe = (const float*)d_in[5];
  float* out = (float*)d_out;                  // reference output dtype = float32

  char* ws = (char*)d_ws;
  const size_t SEG = 8388608;                  // 8192*512*2 bytes (bf16)
  u16* qb  = (u16*)(ws + 0 * SEG);
  u16* kb  = (u16*)(ws + 1 * SEG);
  u16* vb  = (u16*)(ws + 2 * SEG);
  u16* ao  = (u16*)(ws + 3 * SEG);
  u16* lp  = (u16*)(ws + 4 * SEG);
  u16* xb  = (u16*)(ws + 5 * SEG);             // 8192*512 bf16 (written by lepe)
  u16* wqb = (u16*)(ws + 6 * SEG);             // 1536*512 bf16 (1.5 MB)
  u16* wpb = (u16*)(ws + 6 * SEG + 1572864);   // 512*512 bf16 (0.5 MB)

  // lepe grid z: 0,1 = conv halves; 2 = fused weight conversion slice
  hipLaunchKernelGGL(lepe_conv, dim3(32, 8, 3), dim3(256), 0, stream,
                     x, w_lepe, b_lepe, w_qkv, w_proj, lp, xb, wqb, wpb);
  hipLaunchKernelGGL(qkv_gemm, dim3(64, 12), dim3(256), 0, stream, xb, wqb, qb, kb, vb);
  hipLaunchKernelGGL(attn_mfma, dim3(512), dim3(512), 0, stream, qb, kb, vb, lp, ao);
  hipLaunchKernelGGL(proj_gemm, dim3(64, 8), dim3(256), 0, stream, ao, wpb, b_proj, out);
}